// Round 11
// baseline (342.916 us; speedup 1.0000x reference)
//
#include <hip/hip_runtime.h>

#define B_    16
#define N_    65536
#define C_    256
#define DIN_  16
#define DOUT_ 16

typedef float f32x4 __attribute__((ext_vector_type(4)));

// workspace layout (floats):
//   s      [B_][DIN_][C_]    = 65536 floats  (s[b][i][k])
//   off    [B_][C_][DOUT_]   = 65536 floats  (b1-prefilled; k_off atomically
//                                             accumulates invN-scaled partials)
//   wd_t   [C_][DIN_*DOUT_]  = 65536 floats  (wd_t[c][i*16+o])
//   c_of_n [N_]              = 65536 ints    (cluster id of source row n)

// ---------------------------------------------------------------------------
// K1: fused prep + cluster sums (gather form — R0-proven, ~34 µs). Unchanged.
// ---------------------------------------------------------------------------
__global__ __launch_bounds__(256) void k_sum_prep(
    const float* __restrict__ x, const float* __restrict__ w_diag,
    const int* __restrict__ P, const float* __restrict__ b1,
    float* __restrict__ s, float* __restrict__ wd_t,
    int* __restrict__ c_of_n, float* __restrict__ off)
{
    int bid = blockIdx.x;
    int t = threadIdx.x;
    if (bid >= B_ * C_) {
        int r = bid - B_ * C_;
        if (r < 256) {
            int o = r >> 4, i = r & 15;
            wd_t[t * 256 + i * 16 + o] = w_diag[r * C_ + t];  // coalesced read
        } else if (r < 512) {
            int k = r - 256;
            c_of_n[P[k * 256 + t]] = k;
        } else {
            int m = (r - 512) * 256 + t;   // full 65536 coverage
            off[m] = b1[m & 15];
        }
        return;
    }
    int b = bid >> 8;
    int k = bid & (C_ - 1);
    int q  = t & 3;         // which float4 of the 16-float row
    int rg = t >> 2;        // 0..63 row group
    float4 acc = make_float4(0.f, 0.f, 0.f, 0.f);
    const int jbase = k << 8;
    #pragma unroll
    for (int m = 0; m < 4; ++m) {
        int n = P[jbase + rg + 64 * m];
        const float4* row =
            reinterpret_cast<const float4*>(x + ((size_t)(b * N_ + n)) * DIN_);
        float4 v = row[q];
        acc.x += v.x; acc.y += v.y; acc.z += v.z; acc.w += v.w;
    }
    // butterfly reduce over row-groups within the wave (bits 2..5 of lane id)
    #pragma unroll
    for (int mask = 4; mask <= 32; mask <<= 1) {
        acc.x += __shfl_xor(acc.x, mask, 64);
        acc.y += __shfl_xor(acc.y, mask, 64);
        acc.z += __shfl_xor(acc.z, mask, 64);
        acc.w += __shfl_xor(acc.w, mask, 64);
    }
    __shared__ float4 part[4][4];  // [wave][q]
    int lane = t & 63, wave = t >> 6;
    if (lane < 4) part[wave][lane] = acc;  // lane == q for lanes 0..3
    __syncthreads();
    if (t < 16) {
        int qq = t >> 2, comp = t & 3;
        float v = 0.f;
        #pragma unroll
        for (int w = 0; w < 4; ++w) {
            const float* p = reinterpret_cast<const float*>(&part[w][qq]);
            v += p[comp];
        }
        int i = qq * 4 + comp;
        s[(b * DIN_ + i) * C_ + k] = v;   // s[b][i][k]
    }
}

// ---------------------------------------------------------------------------
// K2 (contiguous-granule stream): partial over i-half, atomic-accumulated.
//   off[b,c,o] += invN * sum_{i in half, k} w_off[o,i,c,k] * s[b,i,k]
// grid = 512: cg = bid&15 (c0 = 16*cg), o = (bid>>4)&15, ih = bid>>8.
// KEY CHANGE vs R9/R10: per i, the block's 16 w-rows are c-CONSECUTIVE ->
// one contiguous 16 KB burst (not 16x 1KB granules at 2^18-byte strides,
// which aliased L2 sets / L3 slices and capped w-delivery at ~1.9 TB/s in
// ALL seven prior K2 variants — incl. R6's L3-warm 59.7 us smoking gun).
// 256 threads = 4 waves; wave = b-quad (reads SAME w -> L1 broadcast);
// lane kq = k-quad. acc[cc*4+bb] = 64 regs; wv/sv A/B ping-pong prefetch
// (~235 VGPR, 2 waves/SIMD). 8 i-iters inside -> only 2 atomics/output.
// Tail: 63-shfl fold (R2-verified); lane l holds index bitrev6(l).
// ---------------------------------------------------------------------------
__global__ __launch_bounds__(256) void k_off(
    const float* __restrict__ w_off, const float* __restrict__ s,
    float* __restrict__ off)
{
    const int bid = (int)blockIdx.x;  // 0..511
    const int cg  = bid & 15;
    const int o   = (bid >> 4) & 15;
    const int ih  = bid >> 8;         // i-half
    const int c0  = cg * 16;
    const int t   = threadIdx.x;
    const int kq  = t & 63;
    const int b0  = (t >> 6) * 4;     // wave id -> b-quad

    const float4* w4 = reinterpret_cast<const float4*>(w_off);
    const float4* s4 = reinterpret_cast<const float4*>(s);

    // fl4 index of w_off[o][i][c][4kq] = ((o*16+i)*256+c)*64 + kq
    //   i-stride 16384, c-stride 64 (contiguous rows!)
    const int wbase = ((o * 16 + ih * 8) * 256 + c0) * 64 + kq;
    // fl4 index of s[b][i][4kq] = (b*16+i)*64 + kq
    const int sbase = (b0 * 16 + ih * 8) * 64 + kq;

    float acc[64];   // acc[cc*4 + bb]
    #pragma unroll
    for (int z = 0; z < 64; ++z) acc[z] = 0.f;

    float4 wA[16], sA[4], wB[16], sB[4];

#define LOADG(WV, SV, II)                                                      \
    {                                                                          \
        _Pragma("unroll")                                                      \
        for (int cc = 0; cc < 16; ++cc)                                        \
            WV[cc] = w4[wbase + (II) * 16384 + cc * 64];                       \
        _Pragma("unroll")                                                      \
        for (int bb = 0; bb < 4; ++bb)                                         \
            SV[bb] = s4[sbase + (II) * 64 + bb * 1024];                        \
    }

#define FMAG(WV, SV)                                                           \
    {                                                                          \
        _Pragma("unroll")                                                      \
        for (int cc = 0; cc < 16; ++cc)                                        \
            _Pragma("unroll")                                                  \
            for (int bb = 0; bb < 4; ++bb)                                     \
                acc[cc * 4 + bb] += WV[cc].x * SV[bb].x + WV[cc].y * SV[bb].y  \
                                  + WV[cc].z * SV[bb].z + WV[cc].w * SV[bb].w; \
    }

    LOADG(wA, sA, 0)
    #pragma unroll
    for (int ii = 0; ii < 8; ii += 2) {
        LOADG(wB, sB, ii + 1)
        __builtin_amdgcn_sched_barrier(0);
        FMAG(wA, sA)
        if (ii + 2 < 8) {
            LOADG(wA, sA, ii + 2)
        }
        __builtin_amdgcn_sched_barrier(0);
        FMAG(wB, sB)
    }
#undef LOADG
#undef FMAG

    // fold-halving reduce: 64 values x 64 lanes (63 shfls); lane l ends with
    // the fully k-summed value of original index z = bitrev6(l).
#define FOLD(MASK, CNT)                                                        \
    {                                                                          \
        const bool hi_ = (kq & (MASK)) != 0;                                   \
        _Pragma("unroll")                                                      \
        for (int j = 0; j < (CNT); ++j) {                                      \
            float keep = hi_ ? acc[j + (CNT)] : acc[j];                        \
            float send = hi_ ? acc[j] : acc[j + (CNT)];                        \
            acc[j] = keep + __shfl_xor(send, (MASK), 64);                      \
        }                                                                      \
    }
    FOLD(1, 32) FOLD(2, 16) FOLD(4, 8) FOLD(8, 4) FOLD(16, 2) FOLD(32, 1)
#undef FOLD

    // z = bitrev6(kq) = cc*4 + bb
    int z = ((kq >> 5) & 1) | ((kq >> 3) & 2) | ((kq >> 1) & 4)
          | ((kq << 1) & 8) | ((kq << 3) & 16) | ((kq << 5) & 32);
    int cc = z >> 2;
    int bb = z & 3;
    int b  = b0 + bb;
    int c  = c0 + cc;
    atomicAdd(&off[((b << 8) + c) * DOUT_ + o], acc[0] * (1.0f / (float)N_));
}

// ---------------------------------------------------------------------------
// K3: sequential apply. Non-temporal out stores. (unchanged)
// ---------------------------------------------------------------------------
__global__ __launch_bounds__(256) void k_apply_seq(
    const float* __restrict__ x, const int* __restrict__ c_of_n,
    const float* __restrict__ wd_t, const float* __restrict__ off,
    float* __restrict__ out)
{
    int t = threadIdx.x;
    int lr = t >> 2, q = t & 3;
    int n = blockIdx.x * 64 + lr;
    int c = c_of_n[n];

    const float4* wd4 = reinterpret_cast<const float4*>(wd_t);
    float4 wds[16];
    #pragma unroll
    for (int i = 0; i < 16; ++i) wds[i] = wd4[c * 64 + i * 4 + q];

    const float4* x4   = reinterpret_cast<const float4*>(x);
    const float4* off4 = reinterpret_cast<const float4*>(off);
    f32x4* out4        = reinterpret_cast<f32x4*>(out);

    #pragma unroll 2
    for (int b = 0; b < B_; ++b) {
        size_t rowbase = ((size_t)(b * N_ + n)) * 4;
        float4 x0 = x4[rowbase + 0];
        float4 x1 = x4[rowbase + 1];
        float4 x2 = x4[rowbase + 2];
        float4 x3 = x4[rowbase + 3];
        float4 acc = off4[((size_t)((b << 8) + c)) * 4 + q];
        float xv[16];
        xv[0]=x0.x; xv[1]=x0.y; xv[2]=x0.z; xv[3]=x0.w;
        xv[4]=x1.x; xv[5]=x1.y; xv[6]=x1.z; xv[7]=x1.w;
        xv[8]=x2.x; xv[9]=x2.y; xv[10]=x2.z; xv[11]=x2.w;
        xv[12]=x3.x; xv[13]=x3.y; xv[14]=x3.z; xv[15]=x3.w;
        #pragma unroll
        for (int i = 0; i < 16; ++i) {
            acc.x += xv[i] * wds[i].x;
            acc.y += xv[i] * wds[i].y;
            acc.z += xv[i] * wds[i].z;
            acc.w += xv[i] * wds[i].w;
        }
        f32x4 accv;
        accv.x = acc.x; accv.y = acc.y; accv.z = acc.z; accv.w = acc.w;
        __builtin_nontemporal_store(accv, &out4[rowbase + q]);
    }
}

extern "C" void kernel_launch(void* const* d_in, const int* in_sizes, int n_in,
                              void* d_out, int out_size, void* d_ws, size_t ws_size,
                              hipStream_t stream) {
    const float* x      = (const float*)d_in[0];
    const float* w_diag = (const float*)d_in[1];
    const float* w_off  = (const float*)d_in[2];
    const float* b1     = (const float*)d_in[3];
    const int*   P      = (const int*)d_in[4];
    float* out    = (float*)d_out;
    float* s      = (float*)d_ws;          // 65536 floats (s[b][i][k])
    float* off    = s + 65536;             // 65536 floats
    float* wd_t   = off + 65536;           // 65536 floats
    int*   c_of_n = (int*)(wd_t + 65536);  // 65536 ints

    k_sum_prep<<<B_ * C_ + 768, 256, 0, stream>>>(x, w_diag, P, b1,
                                                  s, wd_t, c_of_n, off);
    k_off<<<512, 256, 0, stream>>>(w_off, s, off);
    k_apply_seq<<<N_ / 64, 256, 0, stream>>>(x, c_of_n, wd_t, off, out);
}